// Round 5
// baseline (300.872 us; speedup 1.0000x reference)
//
#include <hip/hip_runtime.h>

// Problem: B=32, C=256, H=64, W=64.  Positions = 131072.  269 MB streamed.
//
// History (kernel-only times from rocprof):
//   v2 (8 waves/blk, strided pair loads):   99.5 us, HBM 1.35 TB/s
//   v3 (explicit load batches):            124 us   REGRESSION (burst+drain)
//   v4 (16 waves/blk, occ 35->65%):        119 us   BW unchanged -> not occupancy
//   v5 (contiguous 256KB chunks, 2-phase): 108 us   BW ~unchanged -> not "contiguity"
//
// v6 theory: all prior kernels walk power-of-2-congruent addresses in
//   LOCKSTEP: at any instant every stream targets the same phase of the
//   HBM channel-interleave rotation (chunk bases 256KB-aligned, channel
//   steps synchronized) -> only ~half the channels are active at a time
//   -> ceiling ~ 0.5 x 6.3 TB/s = measured ~2.7 TB/s total service rate.
//   The m13 copy ubench (6.29 TB/s) sweeps one contiguous window = all
//   channels always active.
// Fix: fused v2 structure (lowest traffic, no ws round-trip) + per-wave
//   CHANNEL-WALK ROTATION: wave (blk,wv) starts its 32-channel loop at a
//   hashed offset r, c = wv*32 + ((k+r)&31).  Instantaneous footprint
//   spreads over 512 KB at 16 KB granularity with hashed parity ->
//   uniform channel coverage for any interleave period 16K..128K.

#define BB   32
#define CC   256
#define HWSZ 4096                 // H*W floats per plane
#define NPOS (BB * HWSZ)          // 131072 positions
#define HW4  (HWSZ / 4)           // 1024 float4 per plane
#define PPB  256                  // positions per block
#define NW   8                    // waves per block (512 threads)
#define CPW  (CC / NW)            // 32 channels per wave
#define NBLK (NPOS / PPB)         // 512 blocks
#define SIM_EPS 1e-8f

__global__ __launch_bounds__(512) void
sim_reduce_kernel(const float4* __restrict__ u4,
                  const float4* __restrict__ m4,
                  const int*    __restrict__ mask,
                  double*       __restrict__ ws,
                  float*        __restrict__ out)
{
    // Per-wave channel-chunk partials for the block's 256 positions.
    __shared__ float4 s_num[NW][64];
    __shared__ float4 s_uu [NW][64];
    __shared__ float4 s_mm [NW][64];

    const int wv = threadIdx.x >> 6;     // wave id: which 32-channel chunk
    const int l  = threadIdx.x & 63;     // lane: which float4 group of positions

    const int pos0 = blockIdx.x * PPB;   // block's first position
    const int b    = pos0 >> 12;         // pos0 / 4096 (PPB divides HWSZ)
    const int hw0  = pos0 & (HWSZ - 1);

    // Prefetch mask (phase-2 input) so its load overlaps the main loop.
    int mk = 0;
    if (threadIdx.x < PPB) mk = mask[pos0 + threadIdx.x];

    // Channel-phase rotation: hashed start per (block, wave) de-phases the
    // device-wide channel walk (breaks power-of-2 lockstep -> all HBM
    // channels active at every instant).
    const unsigned gid = (unsigned)blockIdx.x * NW + (unsigned)wv;
    const int r = (int)((gid * 2654435761u) >> 27) & (CPW - 1);

    // float4 index of this thread's 4 positions at its chunk's channel 0.
    const size_t base4 = (size_t)b * CC * HW4
                       + (size_t)(wv * CPW) * HW4
                       + (size_t)(hw0 >> 2) + (size_t)l;
    const float4* __restrict__ up = u4 + base4;
    const float4* __restrict__ mp = m4 + base4;

    float4 num = make_float4(0.f, 0.f, 0.f, 0.f);
    float4 uu  = make_float4(0.f, 0.f, 0.f, 0.f);
    float4 mm  = make_float4(0.f, 0.f, 0.f, 0.f);

#pragma unroll 4
    for (int k = 0; k < CPW; ++k) {
        const int c = (k + r) & (CPW - 1);          // rotated channel walk
        const float4 a  = up[(size_t)c * HW4];
        const float4 bv = mp[(size_t)c * HW4];
        num.x = fmaf(a.x, bv.x, num.x);
        num.y = fmaf(a.y, bv.y, num.y);
        num.z = fmaf(a.z, bv.z, num.z);
        num.w = fmaf(a.w, bv.w, num.w);
        uu.x  = fmaf(a.x, a.x,  uu.x);
        uu.y  = fmaf(a.y, a.y,  uu.y);
        uu.z  = fmaf(a.z, a.z,  uu.z);
        uu.w  = fmaf(a.w, a.w,  uu.w);
        mm.x  = fmaf(bv.x, bv.x, mm.x);
        mm.y  = fmaf(bv.y, bv.y, mm.y);
        mm.z  = fmaf(bv.z, bv.z, mm.z);
        mm.w  = fmaf(bv.w, bv.w, mm.w);
    }

    s_num[wv][l] = num;
    s_uu [wv][l] = uu;
    s_mm [wv][l] = mm;
    __syncthreads();

    // Phase 2: first 4 waves combine the 8 channel-chunk partials per
    // position, compute cosine sim, apply mask.
    double sd = 0.0, md = 0.0;
    if (threadIdx.x < PPB) {
        const int t = threadIdx.x;
        float fn = 0.f, fu = 0.f, fm = 0.f;
#pragma unroll
        for (int k = 0; k < NW; ++k) {
            fn += ((const float*)s_num[k])[t];
            fu += ((const float*)s_uu [k])[t];
            fm += ((const float*)s_mm [k])[t];
        }
        const float denom = fmaxf(sqrtf(fu), SIM_EPS) * fmaxf(sqrtf(fm), SIM_EPS);
        const float sim   = fn / denom;
        if (mk != 0) { sd = (double)sim; md = 1.0; }
    }

    // Block reduction: wave shfl (inactive waves contribute 0) -> LDS.
#pragma unroll
    for (int off = 32; off > 0; off >>= 1) {
        sd += __shfl_down(sd, off, 64);
        md += __shfl_down(md, off, 64);
    }

    __shared__ double r_s[NW];
    __shared__ double r_m[NW];
    if (l == 0) { r_s[wv] = sd; r_m[wv] = md; }
    __syncthreads();

    if (threadIdx.x == 0) {
        double ts = 0.0, tm = 0.0;
#pragma unroll
        for (int k = 0; k < NW; ++k) { ts += r_s[k]; tm += r_m[k]; }
        atomicAdd(&ws[0], ts);   // device-scope by default on CDNA
        atomicAdd(&ws[1], tm);
        __threadfence();         // make our adds visible before the ticket
        const unsigned long long prev =
            atomicAdd((unsigned long long*)&ws[2], 1ull);
        if (prev == (unsigned long long)(NBLK - 1)) {
            // Last block: every other block fenced its adds before the
            // ticket increment.  atomicAdd(+0.0) reads are device-coherent.
            const double s  = atomicAdd(&ws[0], 0.0);
            const double mc = atomicAdd(&ws[1], 0.0);
            out[0] = (float)(s / mc);
        }
    }
}

extern "C" void kernel_launch(void* const* d_in, const int* in_sizes, int n_in,
                              void* d_out, int out_size, void* d_ws, size_t ws_size,
                              hipStream_t stream)
{
    const float4* u4   = (const float4*)d_in[0];
    const float4* m4   = (const float4*)d_in[1];
    const int*    mask = (const int*)d_in[2];
    float*  out = (float*)d_out;
    double* ws  = (double*)d_ws;

    // ws is re-poisoned before every timed launch -> zero the two
    // accumulators + the completion ticket on-stream (graph-capture safe).
    hipMemsetAsync(d_ws, 0, 3 * sizeof(double), stream);

    sim_reduce_kernel<<<NBLK, 512, 0, stream>>>(u4, m4, mask, ws, out);
}

// Round 6
// 285.012 us; speedup vs baseline: 1.0556x; 1.0556x over previous
//
#include <hip/hip_runtime.h>

// Problem: B=32, C=256, H=64, W=64.  Positions = 131072.  269 MB streamed.
//
// History (kernel-only times from rocprof):
//   v2 (8 waves/blk, strided pair loads):   99.5 us, HBM 1.35 TB/s, occ 37%
//   v3 (explicit load batches):            124 us   REGRESSION (burst+drain)
//   v4 (16 waves/blk, occ 35->65%):        119 us   BW unchanged -> not occupancy
//   v5 (contiguous 256KB chunks, 2-phase): 108 us   BW unchanged -> not contiguity
//   v6 (hashed channel-walk rotation):     120 us   BW unchanged -> not channel phase
//
// Invariant: total service rate pins at ~2.7 TB/s across ALL structures,
//   VALUBusy ~2%, conflicts 0, occupancy 33-65% with no effect.
//   A per-CU shared cap fits: ~32 L1 miss-lines/CU * 128 B / 900 cy * 2.4 GHz
//   * 256 CU = 2.7 TB/s -- independent of waves and address order.
//
// v7 = within-round A/B probe at identical geometry (v2 structure):
//   dispatch 1: batches b0-15,  NON-TEMPORAL loads (nt bit: no L1/L2 alloc)
//   dispatch 2: batches b16-31, plain loads (control)
//   rocprof reports each dispatch separately -> single-variable comparison,
//   total work unchanged.  Data has zero intra-launch reuse, so nt is also
//   semantically the right policy if it helps.

#define BB   32
#define CC   256
#define HWSZ 4096                 // H*W floats per plane
#define NPOS (BB * HWSZ)          // 131072 positions
#define HW4  (HWSZ / 4)           // 1024 float4 per plane
#define PPB  256                  // positions per block
#define NW   8                    // waves per block (512 threads)
#define CPW  (CC / NW)            // 32 channels per wave
#define NBLK (NPOS / PPB)         // 512 blocks total (both arms)
#define HALFBLK (NBLK / 2)        // 256 blocks per arm
#define SIM_EPS 1e-8f

typedef float f32x4 __attribute__((ext_vector_type(4)));

template<bool NT>
__global__ __launch_bounds__(512) void
sim_half_kernel(const f32x4* __restrict__ u4,
                const f32x4* __restrict__ m4,
                const int*   __restrict__ mask,
                double*      __restrict__ ws,
                float*       __restrict__ out,
                int pos_base)
{
    // Per-wave channel-chunk partials for the block's 256 positions.
    __shared__ f32x4 s_num[NW][64];
    __shared__ f32x4 s_uu [NW][64];
    __shared__ f32x4 s_mm [NW][64];

    const int wv = threadIdx.x >> 6;     // wave id: which 32-channel chunk
    const int l  = threadIdx.x & 63;     // lane: which float4 group of positions

    const int pos0 = pos_base + blockIdx.x * PPB;
    const int b    = pos0 >> 12;         // pos0 / 4096
    const int hw0  = pos0 & (HWSZ - 1);

    // Prefetch mask (phase-2 input) so its load overlaps the main loop.
    int mk = 0;
    if (threadIdx.x < PPB) mk = mask[pos0 + threadIdx.x];

    // float4 index of this thread's 4 positions at its chunk's channel 0.
    const size_t base4 = (size_t)b * CC * HW4
                       + (size_t)(wv * CPW) * HW4
                       + (size_t)(hw0 >> 2) + (size_t)l;
    const f32x4* __restrict__ up = u4 + base4;
    const f32x4* __restrict__ mp = m4 + base4;

    f32x4 num = {0.f, 0.f, 0.f, 0.f};
    f32x4 uu  = {0.f, 0.f, 0.f, 0.f};
    f32x4 mm  = {0.f, 0.f, 0.f, 0.f};

    // v2-style pipelined pair loads (best-measured form); the ONLY
    // difference between arms is the nt bit on the two stream loads.
#pragma unroll 4
    for (int c = 0; c < CPW; ++c) {
        f32x4 a, bv;
        if constexpr (NT) {
            a  = __builtin_nontemporal_load(up + (size_t)c * HW4);
            bv = __builtin_nontemporal_load(mp + (size_t)c * HW4);
        } else {
            a  = up[(size_t)c * HW4];
            bv = mp[(size_t)c * HW4];
        }
        num[0] = fmaf(a[0], bv[0], num[0]);
        num[1] = fmaf(a[1], bv[1], num[1]);
        num[2] = fmaf(a[2], bv[2], num[2]);
        num[3] = fmaf(a[3], bv[3], num[3]);
        uu[0]  = fmaf(a[0], a[0],  uu[0]);
        uu[1]  = fmaf(a[1], a[1],  uu[1]);
        uu[2]  = fmaf(a[2], a[2],  uu[2]);
        uu[3]  = fmaf(a[3], a[3],  uu[3]);
        mm[0]  = fmaf(bv[0], bv[0], mm[0]);
        mm[1]  = fmaf(bv[1], bv[1], mm[1]);
        mm[2]  = fmaf(bv[2], bv[2], mm[2]);
        mm[3]  = fmaf(bv[3], bv[3], mm[3]);
    }

    s_num[wv][l] = num;
    s_uu [wv][l] = uu;
    s_mm [wv][l] = mm;
    __syncthreads();

    // Phase 2: first 4 waves combine the 8 channel-chunk partials per
    // position, compute cosine sim, apply mask.
    double sd = 0.0, md = 0.0;
    if (threadIdx.x < PPB) {
        const int t = threadIdx.x;
        float fn = 0.f, fu = 0.f, fm = 0.f;
#pragma unroll
        for (int k = 0; k < NW; ++k) {
            fn += ((const float*)s_num[k])[t];
            fu += ((const float*)s_uu [k])[t];
            fm += ((const float*)s_mm [k])[t];
        }
        const float denom = fmaxf(sqrtf(fu), SIM_EPS) * fmaxf(sqrtf(fm), SIM_EPS);
        const float sim   = fn / denom;
        if (mk != 0) { sd = (double)sim; md = 1.0; }
    }

    // Block reduction: wave shfl (inactive waves contribute 0) -> LDS.
#pragma unroll
    for (int off = 32; off > 0; off >>= 1) {
        sd += __shfl_down(sd, off, 64);
        md += __shfl_down(md, off, 64);
    }

    __shared__ double r_s[NW];
    __shared__ double r_m[NW];
    if (l == 0) { r_s[wv] = sd; r_m[wv] = md; }
    __syncthreads();

    if (threadIdx.x == 0) {
        double ts = 0.0, tm = 0.0;
#pragma unroll
        for (int k = 0; k < NW; ++k) { ts += r_s[k]; tm += r_m[k]; }
        atomicAdd(&ws[0], ts);   // device-scope by default on CDNA
        atomicAdd(&ws[1], tm);
        __threadfence();         // make our adds visible before the ticket
        const unsigned long long prev =
            atomicAdd((unsigned long long*)&ws[2], 1ull);
        if (prev == (unsigned long long)(NBLK - 1)) {
            // Only reachable in the second dispatch (same stream serializes).
            const double s  = atomicAdd(&ws[0], 0.0);
            const double mc = atomicAdd(&ws[1], 0.0);
            out[0] = (float)(s / mc);
        }
    }
}

extern "C" void kernel_launch(void* const* d_in, const int* in_sizes, int n_in,
                              void* d_out, int out_size, void* d_ws, size_t ws_size,
                              hipStream_t stream)
{
    const f32x4* u4   = (const f32x4*)d_in[0];
    const f32x4* m4   = (const f32x4*)d_in[1];
    const int*   mask = (const int*)d_in[2];
    float*  out = (float*)d_out;
    double* ws  = (double*)d_ws;

    // ws is re-poisoned before every timed launch -> zero the two
    // accumulators + the completion ticket on-stream (graph-capture safe).
    hipMemsetAsync(d_ws, 0, 3 * sizeof(double), stream);

    // Arm A (probe): batches 0-15 with non-temporal loads.
    sim_half_kernel<true ><<<HALFBLK, 512, 0, stream>>>(u4, m4, mask, ws, out, 0);
    // Arm B (control): batches 16-31 with plain loads.
    sim_half_kernel<false><<<HALFBLK, 512, 0, stream>>>(u4, m4, mask, ws, out,
                                                        HALFBLK * PPB);
}